// Round 7
// baseline (1068.314 us; speedup 1.0000x reference)
//
#include <hip/hip_runtime.h>
#include <hip/hip_fp16.h>

#define BB 512
#define TT 512
#define EE 100
#define HH 40
#define GG 120   // 3*HH
#define TC 128   // timesteps per chunk
#define NC 4     // chunks

typedef _Float16 h2_t __attribute__((ext_vector_type(2)));

__device__ __forceinline__ float fdot2_(h2_t a, h2_t b, float c) {
    return __builtin_amdgcn_fdot2(a, b, c, false);
}
__device__ __forceinline__ h2_t pack2_(float x, float y) {
    h2_t r; r[0] = (_Float16)x; r[1] = (_Float16)y; return r;
}
__device__ __forceinline__ float sigmoid_(float x) {
    return 1.0f / (1.0f + __expf(-x));
}
__device__ __forceinline__ float tanhfast_(float x) {
    float e = __expf(2.0f * x);
    return 1.0f - 2.0f / (e + 1.0f);
}

// Standalone input-side GEMM (unfused this round for per-dispatch
// attribution: fused dispatches hid which half ate the 48-56us).
// 64 rows x 128 cols (120 valid) per block, 4x8 micro-tile, fp16 dot2.
// launch_bounds(256,4): GEMM only needs ~70 VGPRs -> 4 blocks/CU (fusion
// had chained it to the scan's 2-blocks/CU bounds).
// grid: 2048 blocks = (b 0..511) x (row-tile 0..1) x (dir 0..1).
template<int K, bool GATHER>
__global__ __launch_bounds__(256, 4) void gx_gemm(
    const int ci,
    const int* __restrict__ text, const float* __restrict__ emb,
    const __half* __restrict__ Xh,
    const float* __restrict__ Wf, const float* __restrict__ bf,
    const float* __restrict__ Wb, const float* __restrict__ bb,
    __half* __restrict__ gx)
{
    constexpr int K2 = K / 2, KQ = K / 4;
    __shared__ h2_t Xs2[K2 * 64];    // k-pair-major: [k2][row]
    __shared__ h2_t Ws2[K2 * 128];   // k-pair-major: [k2][col]
    const int tid = threadIdx.x;
    const int gid = blockIdx.x;
    const int b   = gid & (BB - 1);
    const int rt  = (gid >> 9) & 1;
    const int dir = gid >> 10;
    const int chunk = dir ? (NC - 1 - ci) : ci;
    const int trow0 = chunk * TC + rt * 64;   // global t of tile row 0
    const float* W    = dir ? Wb : Wf;
    const float* bias = dir ? bb : bf;

    // stage X (k-pair-major)
    if (GATHER) {
        for (int idx = tid; idx < 64 * KQ; idx += 256) {
            const int r = idx & 63, q = idx >> 6;
            const int tok = text[b * TT + trow0 + r];
            const float4 v = ((const float4*)emb)[(size_t)tok * KQ + q];
            Xs2[(2*q+0)*64 + r] = pack2_(v.x, v.y);
            Xs2[(2*q+1)*64 + r] = pack2_(v.z, v.w);
        }
    } else {
        constexpr int KQ8 = K / 8;
        for (int idx = tid; idx < 64 * KQ8; idx += 256) {
            const int r = idx & 63, q = idx >> 6;
            union { float4 f; h2_t h[4]; } u;
            u.f = ((const float4*)Xh)[((size_t)b * TT + trow0 + r) * KQ8 + q];
            #pragma unroll
            for (int i2 = 0; i2 < 4; ++i2)
                Xs2[(4*q + i2)*64 + r] = u.h[i2];
        }
    }
    // stage W (k-pair-major), 120 valid cols padded to 128
    for (int idx = tid; idx < 128 * KQ; idx += 256) {
        const int c = idx & 127, q = idx >> 7;
        float4 v = make_float4(0.f, 0.f, 0.f, 0.f);
        if (c < GG) v = ((const float4*)W)[(size_t)c * KQ + q];
        Ws2[(2*q+0)*128 + c] = pack2_(v.x, v.y);
        Ws2[(2*q+1)*128 + c] = pack2_(v.z, v.w);
    }
    __syncthreads();

    const int tx = tid & 15, ty = tid >> 4;   // cols tx*8..+7, rows ty*4..+3
    float acc[4][8] = {};
    #pragma unroll 2
    for (int k2 = 0; k2 < K2; ++k2) {
        union { float4 f; h2_t h[4]; } xa, w0, w1;
        xa.f = *(const float4*)(Xs2 + k2*64  + (ty << 2));   // 4 rows
        w0.f = *(const float4*)(Ws2 + k2*128 + (tx << 3));   // cols 0..3
        w1.f = *(const float4*)(Ws2 + k2*128 + (tx << 3) + 4); // cols 4..7
        #pragma unroll
        for (int i = 0; i < 4; ++i) {
            #pragma unroll
            for (int j2 = 0; j2 < 4; ++j2) {
                acc[i][j2]     = fdot2_(xa.h[i], w0.h[j2], acc[i][j2]);
                acc[i][4 + j2] = fdot2_(xa.h[i], w1.h[j2], acc[i][4 + j2]);
            }
        }
    }

    if (tx < 15) {   // cols 120..127 invalid -> tx==15 discards
        const int c = tx << 3;
        float bv[8];
        #pragma unroll
        for (int j2 = 0; j2 < 8; ++j2) bv[j2] = bias[c + j2];
        const size_t rowB = ((size_t)dir * BB + b) * TC + rt * 64;
        #pragma unroll
        for (int i = 0; i < 4; ++i) {
            union { float4 f; __half2 h[4]; } u;
            #pragma unroll
            for (int j2 = 0; j2 < 4; ++j2)
                u.h[j2] = __floats2half2_rn(acc[i][2*j2] + bv[2*j2],
                                            acc[i][2*j2+1] + bv[2*j2+1]);
            *(float4*)(gx + (rowB + (ty << 2) + i) * GG + c) = u.f;
        }
    }
}

// Standalone scan: one 64-thread block = one wave = BOTH directions of one
// batch (two independent chains interleaved -> latency shared). Lane j<40
// owns channel j of both chains. fp16 weights, both dirs = 120 VGPRs,
// resident under __launch_bounds__(64,1) (VGPR cap 512 -> no r4-style
// spill). h broadcast via per-block LDS fp16 vector (in-order DS, no
// barrier); ds_write issued immediately after hn. 2-deep gx queue.
template<int LAYER>
__global__ __launch_bounds__(64, 1) void gru_scan(
    const int ci,
    const __half* __restrict__ gx,
    const float* __restrict__ WhhF, const float* __restrict__ bhhF,
    const float* __restrict__ WhhB, const float* __restrict__ bhhB,
    const int* __restrict__ lens,
    __half* __restrict__ out0,
    float* __restrict__ hcar, float* __restrict__ hlast,
    float* __restrict__ sumb, float* __restrict__ maxb)
{
    __shared__ __align__(16) _Float16 hFs[48];
    __shared__ __align__(16) _Float16 hBs[48];
    const int b = blockIdx.x;
    const int j = threadIdx.x;
    if (j >= HH) return;

    // weights both dirs, fp16-packed: 120 VGPRs
    h2_t WrF[HH/2], WzF[HH/2], WnF[HH/2], WrB[HH/2], WzB[HH/2], WnB[HH/2];
    {
        const float4* rf = (const float4*)(WhhF + (size_t)(0*HH + j) * HH);
        const float4* zf = (const float4*)(WhhF + (size_t)(1*HH + j) * HH);
        const float4* nf = (const float4*)(WhhF + (size_t)(2*HH + j) * HH);
        const float4* rb = (const float4*)(WhhB + (size_t)(0*HH + j) * HH);
        const float4* zb = (const float4*)(WhhB + (size_t)(1*HH + j) * HH);
        const float4* nb = (const float4*)(WhhB + (size_t)(2*HH + j) * HH);
        #pragma unroll
        for (int q = 0; q < HH/4; ++q) {
            float4 v;
            v = rf[q]; WrF[2*q] = pack2_(v.x,v.y); WrF[2*q+1] = pack2_(v.z,v.w);
            v = zf[q]; WzF[2*q] = pack2_(v.x,v.y); WzF[2*q+1] = pack2_(v.z,v.w);
            v = nf[q]; WnF[2*q] = pack2_(v.x,v.y); WnF[2*q+1] = pack2_(v.z,v.w);
            v = rb[q]; WrB[2*q] = pack2_(v.x,v.y); WrB[2*q+1] = pack2_(v.z,v.w);
            v = zb[q]; WzB[2*q] = pack2_(v.x,v.y); WzB[2*q+1] = pack2_(v.z,v.w);
            v = nb[q]; WnB[2*q] = pack2_(v.x,v.y); WnB[2*q+1] = pack2_(v.z,v.w);
        }
    }
    const float brF = bhhF[j], bzF = bhhF[HH+j], bnF = bhhF[2*HH+j];
    const float brB = bhhB[j], bzB = bhhB[HH+j], bnB = bhhB[2*HH+j];
    const int len = lens[b];
    const int tbF = ci * TC;
    const int tbB = (NC - 1 - ci) * TC;

    float hf = (ci == 0) ? 0.0f : hcar[(size_t)(0*BB + b) * HH + j];
    float hb = (ci == 0) ? 0.0f : hcar[(size_t)(1*BB + b) * HH + j];
    hFs[j] = (_Float16)hf;
    hBs[j] = (_Float16)hb;
    float psF = 0.f, pmF = -3.4e38f, psB = 0.f, pmB = -3.4e38f;
    const size_t rowF = ((size_t)0 * BB + b) * TC;
    const size_t rowB = ((size_t)1 * BB + b) * TC;

    // 2-deep gx queues (slot d = step s0+d)
    __half qrF[2], qzF[2], qnF[2], qrB[2], qzB[2], qnB[2];
    #pragma unroll
    for (int d = 0; d < 2; ++d) {
        const __half* gF = gx + (rowF + d) * GG;
        const __half* gB = gx + (rowB + (TC - 1 - d)) * GG;
        qrF[d] = gF[j]; qzF[d] = gF[HH + j]; qnF[d] = gF[2*HH + j];
        qrB[d] = gB[j]; qzB[d] = gB[HH + j]; qnB[d] = gB[2*HH + j];
    }

    const float4* hf4 = (const float4*)hFs;
    const float4* hb4 = (const float4*)hBs;

    #define STEP(S, U)                                                         \
    {                                                                          \
        const int s_ = (S);                                                    \
        const int tF = tbF + s_;                                               \
        const int tB = tbB + (TC - 1 - s_);                                    \
        const float grF = __half2float(qrF[U]);                                \
        const float gzF = __half2float(qzF[U]);                                \
        const float gnF = __half2float(qnF[U]);                                \
        const float grB = __half2float(qrB[U]);                                \
        const float gzB = __half2float(qzB[U]);                                \
        const float gnB = __half2float(qnB[U]);                                \
        if (s_ < TC - 2) {   /* refill slot U with step s_+2 */                \
            const __half* gF_ = gx + (rowF + s_ + 2) * GG;                     \
            const __half* gB_ = gx + (rowB + (TC - 3 - s_)) * GG;              \
            qrF[U] = gF_[j]; qzF[U] = gF_[HH + j]; qnF[U] = gF_[2*HH + j];     \
            qrB[U] = gB_[j]; qzB[U] = gB_[HH + j]; qnB[U] = gB_[2*HH + j];     \
        }                                                                      \
        float rF0 = brF, rF1 = 0.f, zF0 = bzF, zF1 = 0.f, nF0 = bnF, nF1 = 0.f;\
        float rB0 = brB, rB1 = 0.f, zB0 = bzB, zB1 = 0.f, nB0 = bnB, nB1 = 0.f;\
        _Pragma("unroll")                                                      \
        for (int q = 0; q < 5; ++q) {                                          \
            union { float4 f; h2_t h[4]; } uf, ub;                             \
            uf.f = hf4[q]; ub.f = hb4[q];                                      \
            rF0 = fdot2_(WrF[4*q+0], uf.h[0], rF0);                            \
            zF0 = fdot2_(WzF[4*q+0], uf.h[0], zF0);                            \
            nF0 = fdot2_(WnF[4*q+0], uf.h[0], nF0);                            \
            rB0 = fdot2_(WrB[4*q+0], ub.h[0], rB0);                            \
            zB0 = fdot2_(WzB[4*q+0], ub.h[0], zB0);                            \
            nB0 = fdot2_(WnB[4*q+0], ub.h[0], nB0);                            \
            rF1 = fdot2_(WrF[4*q+1], uf.h[1], rF1);                            \
            zF1 = fdot2_(WzF[4*q+1], uf.h[1], zF1);                            \
            nF1 = fdot2_(WnF[4*q+1], uf.h[1], nF1);                            \
            rB1 = fdot2_(WrB[4*q+1], ub.h[1], rB1);                            \
            zB1 = fdot2_(WzB[4*q+1], ub.h[1], zB1);                            \
            nB1 = fdot2_(WnB[4*q+1], ub.h[1], nB1);                            \
            rF0 = fdot2_(WrF[4*q+2], uf.h[2], rF0);                            \
            zF0 = fdot2_(WzF[4*q+2], uf.h[2], zF0);                            \
            nF0 = fdot2_(WnF[4*q+2], uf.h[2], nF0);                            \
            rB0 = fdot2_(WrB[4*q+2], ub.h[2], rB0);                            \
            zB0 = fdot2_(WzB[4*q+2], ub.h[2], zB0);                            \
            nB0 = fdot2_(WnB[4*q+2], ub.h[2], nB0);                            \
            rF1 = fdot2_(WrF[4*q+3], uf.h[3], rF1);                            \
            zF1 = fdot2_(WzF[4*q+3], uf.h[3], zF1);                            \
            nF1 = fdot2_(WnF[4*q+3], uf.h[3], nF1);                            \
            rB1 = fdot2_(WrB[4*q+3], ub.h[3], rB1);                            \
            zB1 = fdot2_(WzB[4*q+3], ub.h[3], zB1);                            \
            nB1 = fdot2_(WnB[4*q+3], ub.h[3], nB1);                            \
        }                                                                      \
        const float rrF = sigmoid_(grF + rF0 + rF1);                           \
        const float rrB = sigmoid_(grB + rB0 + rB1);                           \
        const float zzF = sigmoid_(gzF + zF0 + zF1);                           \
        const float zzB = sigmoid_(gzB + zB0 + zB1);                           \
        const float nnF = tanhfast_(gnF + rrF * (nF0 + nF1));                  \
        const float nnB = tanhfast_(gnB + rrB * (nB0 + nB1));                  \
        const float hnF = (1.0f - zzF) * nnF + zzF * hf;                       \
        const float hnB = (1.0f - zzB) * nnB + zzB * hb;                       \
        const bool vF = (tF < len), vB = (tB < len);                           \
        hf = vF ? hnF : hf;                                                    \
        hb = vB ? hnB : hb;                                                    \
        hFs[j] = (_Float16)hf;     /* broadcast ASAP for next step */          \
        hBs[j] = (_Float16)hb;                                                 \
        const float ovF = vF ? hnF : 0.0f;                                     \
        const float ovB = vB ? hnB : 0.0f;                                     \
        if (LAYER == 0) {                                                      \
            out0[((size_t)b * TT + tF) * (2*HH) + j]      = __float2half(ovF); \
            out0[((size_t)b * TT + tB) * (2*HH) + HH + j] = __float2half(ovB); \
        } else {                                                               \
            psF += ovF; if (vF) pmF = fmaxf(pmF, hnF);                         \
            psB += ovB; if (vB) pmB = fmaxf(pmB, hnB);                         \
        }                                                                      \
    }

    for (int s0 = 0; s0 < TC; s0 += 2) {
        STEP(s0 + 0, 0)
        STEP(s0 + 1, 1)
    }
    #undef STEP

    hcar[(size_t)(0*BB + b) * HH + j] = hf;
    hcar[(size_t)(1*BB + b) * HH + j] = hb;
    if (ci == NC - 1) {
        hlast[((size_t)(LAYER*2 + 0) * BB + b) * HH + j] = hf;
        hlast[((size_t)(LAYER*2 + 1) * BB + b) * HH + j] = hb;
    }
    if (LAYER == 1) {
        const size_t piF = (size_t)b * (2*HH) + j;
        const size_t piB = piF + HH;
        if (ci == 0) { sumb[piF] = psF; maxb[piF] = pmF;
                       sumb[piB] = psB; maxb[piB] = pmB; }
        else { sumb[piF] += psF; maxb[piF] = fmaxf(maxb[piF], pmF);
               sumb[piB] += psB; maxb[piB] = fmaxf(maxb[piB], pmB); }
    }
}

// pool_cat = [hb1, hf1, hb0, hf0, avg(80), max(80)] -> fc1(128) -> lrelu -> fc2(1)
__global__ __launch_bounds__(128) void fc_kernel(
    const float* __restrict__ hlast, const float* __restrict__ sumb,
    const float* __restrict__ maxb, const int* __restrict__ lens,
    const float* __restrict__ fc1W, const float* __restrict__ fc1b,
    const float* __restrict__ fc2W, const float* __restrict__ fc2b,
    float* __restrict__ out)
{
    __shared__ float pool[8 * HH];
    __shared__ float red[128];
    const int b = blockIdx.x, tid = threadIdx.x;
    if (tid < HH) {
        pool[tid]        = hlast[(size_t)(3*BB + b) * HH + tid]; // hb1
        pool[HH + tid]   = hlast[(size_t)(2*BB + b) * HH + tid]; // hf1
        pool[2*HH + tid] = hlast[(size_t)(1*BB + b) * HH + tid]; // hb0
        pool[3*HH + tid] = hlast[(size_t)(0*BB + b) * HH + tid]; // hf0
    }
    const float invLen = 1.0f / (float)lens[b];
    if (tid < 2*HH) {
        pool[4*HH + tid] = sumb[(size_t)b * 2*HH + tid] * invLen;
        pool[6*HH + tid] = maxb[(size_t)b * 2*HH + tid];
    }
    __syncthreads();
    float acc = fc1b[tid];
    for (int k = 0; k < 8*HH; ++k)
        acc = fmaf(pool[k], fc1W[(size_t)tid * (8*HH) + k], acc);
    float v = (acc >= 0.0f) ? acc : 0.01f * acc;
    red[tid] = v * fc2W[tid];
    __syncthreads();
    for (int s = 64; s > 0; s >>= 1) {
        if (tid < s) red[tid] += red[tid + s];
        __syncthreads();
    }
    if (tid == 0) out[b] = red[0] + fc2b[0];
}

extern "C" void kernel_launch(void* const* d_in, const int* in_sizes, int n_in,
                              void* d_out, int out_size, void* d_ws, size_t ws_size,
                              hipStream_t stream) {
    const int*   text  = (const int*)d_in[0];
    const int*   lens  = (const int*)d_in[1];
    const float* emb   = (const float*)d_in[2];
    const float* Wih0f = (const float*)d_in[3];
    const float* Whh0f = (const float*)d_in[4];
    const float* bih0f = (const float*)d_in[5];
    const float* bhh0f = (const float*)d_in[6];
    const float* Wih0b = (const float*)d_in[7];
    const float* Whh0b = (const float*)d_in[8];
    const float* bih0b = (const float*)d_in[9];
    const float* bhh0b = (const float*)d_in[10];
    const float* Wih1f = (const float*)d_in[11];
    const float* Whh1f = (const float*)d_in[12];
    const float* bih1f = (const float*)d_in[13];
    const float* bhh1f = (const float*)d_in[14];
    const float* Wih1b = (const float*)d_in[15];
    const float* Whh1b = (const float*)d_in[16];
    const float* bih1b = (const float*)d_in[17];
    const float* bhh1b = (const float*)d_in[18];
    const float* fc1W  = (const float*)d_in[19];
    const float* fc1b  = (const float*)d_in[20];
    const float* fc2W  = (const float*)d_in[21];
    const float* fc2b  = (const float*)d_in[22];
    float* out = (float*)d_out;

    // ws: gx fp16 [2,B,TC,GG] 31.46MB (single buffer: launches are serial)
    //   | out0 fp16 [B,T,80] 41.94MB | hcar | hlast | sumb | maxb  ~74.2MB
    char* p = (char*)d_ws;
    __half* gx    = (__half*)p;  p += (size_t)2 * BB * TC * GG * sizeof(__half);
    __half* out0  = (__half*)p;  p += (size_t)BB * TT * 2 * HH * sizeof(__half);
    float*  hcar  = (float*)p;   p += (size_t)2 * BB * HH * sizeof(float);
    float*  hlast = (float*)p;   p += (size_t)4 * BB * HH * sizeof(float);
    float*  sumb  = (float*)p;   p += (size_t)BB * 2 * HH * sizeof(float);
    float*  maxb  = (float*)p;

    const int NGB = BB * 2 * 2;  // 2048 gemm blocks (b x row-tile x dir)

    // ---- layer 0 ----
    for (int ci = 0; ci < NC; ++ci) {
        gx_gemm<EE, true><<<NGB, 256, 0, stream>>>(ci, text, emb, nullptr,
            Wih0f, bih0f, Wih0b, bih0b, gx);
        gru_scan<0><<<BB, 64, 0, stream>>>(ci, gx,
            Whh0f, bhh0f, Whh0b, bhh0b, lens, out0, hcar, hlast, sumb, maxb);
    }
    // ---- layer 1 ----
    for (int ci = 0; ci < NC; ++ci) {
        gx_gemm<2*HH, false><<<NGB, 256, 0, stream>>>(ci, nullptr, nullptr, out0,
            Wih1f, bih1f, Wih1b, bih1b, gx);
        gru_scan<1><<<BB, 64, 0, stream>>>(ci, gx,
            Whh1f, bhh1f, Whh1b, bhh1b, lens, out0, hcar, hlast, sumb, maxb);
    }
    // ---- head ----
    fc_kernel<<<BB, 128, 0, stream>>>(hlast, sumb, maxb, lens,
        fc1W, fc1b, fc2W, fc2b, out);
}